// Round 8
// baseline (203.353 us; speedup 1.0000x reference)
//
#include <hip/hip_runtime.h>

// SSIM loss v7: wave-per-stripe TH=10, fully-unrolled mod-6 ring rotation,
// DPP wave_shr1/shl1 halo exchange (zero-pad via bound_ctrl, no shuffles),
// pkrtz packing, fused last-wave finalize.

namespace {
constexpr int W = 320, H = 320, B = 128;
constexpr int TH = 10;
constexpr int NSTRIPE = H / TH;        // 32
constexpr int WPB = 4;                 // waves per block
constexpr int NWAVE = B * NSTRIPE;     // 4096
constexpr int NBLK = NWAVE / WPB;      // 1024
constexpr float C1 = 1.0e-4f;
constexpr float C2 = 9.0e-4f;
constexpr int NSLOT = 128;
constexpr int SSTR = 16;               // floats between slots (64 B)
}

typedef _Float16 h2 __attribute__((ext_vector_type(2)));

__device__ __forceinline__ float fdot2f(h2 a, h2 b, float c) {
#if __has_builtin(__builtin_amdgcn_fdot2)
  return __builtin_amdgcn_fdot2(a, b, c, false);
#else
  return fmaf((float)a.x, (float)b.x, fmaf((float)a.y, (float)b.y, c));
#endif
}

__device__ __forceinline__ float rcpf(float x) {
  float r;
  asm("v_rcp_f32 %0, %1" : "=v"(r) : "v"(x));
  return r;
}

__device__ __forceinline__ h2 pack2(float a, float b) {
  return h2{(_Float16)a, (_Float16)b};
}

__device__ __forceinline__ h2 pkrtz(float a, float b) {
#if __has_builtin(__builtin_amdgcn_cvt_pkrtz)
  return __builtin_bit_cast(h2, __builtin_amdgcn_cvt_pkrtz(a, b));
#else
  return pack2(a, b);
#endif
}

// lane i <- lane i-1 (lane 0 <- 0): DPP wave_shr:1, bound_ctrl=1.
__device__ __forceinline__ h2 dpp_up1(h2 v) {
  int r = __builtin_amdgcn_update_dpp(0, __builtin_bit_cast(int, v),
                                      0x138, 0xF, 0xF, true);
  return __builtin_bit_cast(h2, r);
}
// lane i <- lane i+1 (lane 63 <- 0): DPP wave_shl:1, bound_ctrl=1.
__device__ __forceinline__ h2 dpp_dn1(h2 v) {
  int r = __builtin_amdgcn_update_dpp(0, __builtin_bit_cast(int, v),
                                      0x130, 0xF, 0xF, true);
  return __builtin_bit_cast(h2, r);
}

// ---- macros (expand inside kernel; P,T,y0,rp,rt,wAv,wBv,WH,acc) ----

#define LOADQ_NC(PP, QA, QB, QC, QD)                                          \
  do {                                                                        \
    const float* p_ = P + (y0 - 5 + 2 * (PP)) * W;                            \
    const float* t_ = T + (y0 - 5 + 2 * (PP)) * W;                            \
    _Pragma("unroll") for (int c_ = 0; c_ < 5; ++c_) {                        \
      QA[c_] = p_[c_];     QB[c_] = t_[c_];                                   \
      QC[c_] = p_[W + c_]; QD[c_] = t_[W + c_];                               \
    }                                                                         \
  } while (0)

#define LOADQ_CK(PP, QA, QB, QC, QD)                                          \
  do {                                                                        \
    const int r0_ = y0 - 5 + 2 * (PP);                                        \
    if (r0_ >= 0 && r0_ < H) {                                                \
      const float* p_ = P + r0_ * W;                                          \
      const float* t_ = T + r0_ * W;                                          \
      _Pragma("unroll") for (int c_ = 0; c_ < 5; ++c_) {                      \
        QA[c_] = p_[c_]; QB[c_] = t_[c_];                                     \
      }                                                                       \
    } else {                                                                  \
      _Pragma("unroll") for (int c_ = 0; c_ < 5; ++c_) {                      \
        QA[c_] = 0.f; QB[c_] = 0.f;                                           \
      }                                                                       \
    }                                                                         \
    if (r0_ + 1 >= 0 && r0_ + 1 < H) {                                        \
      const float* p_ = P + (r0_ + 1) * W;                                    \
      const float* t_ = T + (r0_ + 1) * W;                                    \
      _Pragma("unroll") for (int c_ = 0; c_ < 5; ++c_) {                      \
        QC[c_] = p_[c_]; QD[c_] = t_[c_];                                     \
      }                                                                       \
    } else {                                                                  \
      _Pragma("unroll") for (int c_ = 0; c_ < 5; ++c_) {                      \
        QC[c_] = 0.f; QD[c_] = 0.f;                                           \
      }                                                                       \
    }                                                                         \
  } while (0)

#define PACK_SLOT(S, QA, QB, QC, QD)                                          \
  do {                                                                        \
    _Pragma("unroll") for (int c_ = 0; c_ < 5; ++c_) {                        \
      rp[S][c_] = pkrtz(QA[c_], QC[c_]);                                      \
      rt[S][c_] = pkrtz(QB[c_], QD[c_]);                                      \
    }                                                                         \
  } while (0)

#define VBLUR_CH(I, CH, PKOUT)                                                \
  do {                                                                        \
    _Pragma("unroll") for (int c_ = 0; c_ < 5; ++c_) {                        \
      float aA_ = 0.f, aB_ = 0.f;                                             \
      _Pragma("unroll") for (int j_ = 0; j_ < 6; ++j_) {                      \
        const h2 a_ = rp[((I) + j_) % 6][c_];                                 \
        const h2 b_ = rt[((I) + j_) % 6][c_];                                 \
        const h2 v_ = (CH) == 0   ? a_                                        \
                      : (CH) == 1 ? b_                                        \
                      : (CH) == 2 ? a_ * a_                                   \
                      : (CH) == 3 ? b_ * b_                                   \
                                  : a_ * b_;                                  \
        aA_ = fdot2f(wAv[j_], v_, aA_);                                       \
        aB_ = fdot2f(wBv[j_], v_, aB_);                                       \
      }                                                                       \
      PKOUT[c_] = pkrtz(aA_, aB_);                                            \
    }                                                                         \
  } while (0)

// DPP halo: 10 VALU movs per channel, zero-pad built in.
#define HALO(PKc, L, R)                                                       \
  do {                                                                        \
    _Pragma("unroll") for (int c_ = 0; c_ < 5; ++c_) {                        \
      L[c_] = dpp_up1(PKc[c_]);                                               \
      R[c_] = dpp_dn1(PKc[c_]);                                               \
    }                                                                         \
  } while (0)

#define HBLUR(PKc, L, R, O)                                                   \
  do {                                                                        \
    _Pragma("unroll") for (int c_ = 0; c_ < 5; ++c_) {                        \
      h2 s1_ = WH[0] * ((c_ + 0 < 5) ? L[c_] : PKc[c_ - 5]);                  \
      _Pragma("unroll") for (int k_ = 1; k_ < 5; ++k_) {                      \
        const int i_ = c_ + k_;                                               \
        s1_ = WH[k_] * ((i_ < 5) ? L[i_] : PKc[i_ - 5]) + s1_;                \
      }                                                                       \
      h2 s2_ = WH[10] * R[c_];                                                \
      _Pragma("unroll") for (int k_ = 9; k_ >= 5; --k_) {                     \
        const int i_ = c_ + k_;                                               \
        s2_ = WH[k_] * ((i_ < 10) ? PKc[i_ - 5] : R[i_ - 10]) + s2_;          \
      }                                                                       \
      O[c_] = s1_ + s2_;                                                      \
    }                                                                         \
  } while (0)

#define SSIM_ACC(O)                                                           \
  do {                                                                        \
    _Pragma("unroll") for (int c_ = 0; c_ < 5; ++c_) {                        \
      _Pragma("unroll") for (int r_ = 0; r_ < 2; ++r_) {                      \
        const float mx_ = r_ ? (float)O[0][c_].y : (float)O[0][c_].x;         \
        const float my_ = r_ ? (float)O[1][c_].y : (float)O[1][c_].x;         \
        const float xx_ = r_ ? (float)O[2][c_].y : (float)O[2][c_].x;         \
        const float yy_ = r_ ? (float)O[3][c_].y : (float)O[3][c_].x;         \
        const float xy_ = r_ ? (float)O[4][c_].y : (float)O[4][c_].x;         \
        const float mxx_ = mx_ * mx_, myy_ = my_ * my_, mxy_ = mx_ * my_;     \
        const float vx_ = xx_ - mxx_, vy_ = yy_ - myy_, vxy_ = xy_ - mxy_;    \
        const float num_ = (2.f * mxy_ + C1) * (2.f * vxy_ + C2);             \
        const float den_ = (mxx_ + myy_ + C1) * (vx_ + vy_ + C2);             \
        acc = fmaf(num_, rcpf(den_), acc);                                    \
      }                                                                       \
    }                                                                         \
  } while (0)

#define COMPUTE(I)                                                            \
  do {                                                                        \
    h2 OUT[5][5];                                                             \
    _Pragma("unroll") for (int ch_ = 0; ch_ < 5; ++ch_) {                     \
      h2 pk_[5], L_[5], R_[5];                                                \
      VBLUR_CH(I, ch_, pk_);                                                  \
      HALO(pk_, L_, R_);                                                      \
      HBLUR(pk_, L_, R_, OUT[ch_]);                                           \
    }                                                                         \
    SSIM_ACC(OUT);                                                            \
  } while (0)

__global__ __launch_bounds__(256) void ssim_main(
    const float* __restrict__ pred, const float* __restrict__ targ,
    float* __restrict__ sink, int* __restrict__ cnt, int nslot, int sstr,
    float* __restrict__ out) {
  const int lane = threadIdx.x & 63;
  const int stripe = __builtin_amdgcn_readfirstlane(
      blockIdx.x * WPB + (threadIdx.x >> 6));
  const int img = stripe / NSTRIPE;
  const int y0  = (stripe % NSTRIPE) * TH;

  const float* __restrict__ P = pred + (size_t)img * (W * H) + 5 * lane;
  const float* __restrict__ T = targ + (size_t)img * (W * H) + 5 * lane;

  constexpr float WF[11] = {0.00102838f, 0.00759885f, 0.03600081f, 0.10936069f,
                            0.21300553f, 0.26601171f, 0.21300553f, 0.10936069f,
                            0.03600081f, 0.00759885f, 0.00102838f};
  const h2 wAv[6] = {pack2(WF[0], WF[1]),  pack2(WF[2], WF[3]),
                     pack2(WF[4], WF[5]),  pack2(WF[6], WF[7]),
                     pack2(WF[8], WF[9]),  pack2(WF[10], 0.f)};
  const h2 wBv[6] = {pack2(0.f, WF[0]),    pack2(WF[1], WF[2]),
                     pack2(WF[3], WF[4]),  pack2(WF[5], WF[6]),
                     pack2(WF[7], WF[8]),  pack2(WF[9], WF[10])};
  h2 WH[11];
#pragma unroll
  for (int k = 0; k < 11; ++k) WH[k] = pack2(WF[k], WF[k]);

  h2 rp[6][5], rt[6][5];
  float acc = 0.f;

  if (y0 >= 5 && y0 + 14 < H) {
    // ---------- interior: fully unrolled, mod-6 ring rotation ----------
    float qa[5], qb[5], qc[5], qd[5];
    float qe[5], qf[5], qg[5], qh[5];
    LOADQ_NC(0, qa, qb, qc, qd);
    LOADQ_NC(1, qe, qf, qg, qh);
    PACK_SLOT(0, qa, qb, qc, qd);
    LOADQ_NC(2, qa, qb, qc, qd);
    PACK_SLOT(1, qe, qf, qg, qh);
    LOADQ_NC(3, qe, qf, qg, qh);
    PACK_SLOT(2, qa, qb, qc, qd);
    LOADQ_NC(4, qa, qb, qc, qd);
    PACK_SLOT(3, qe, qf, qg, qh);
    LOADQ_NC(5, qe, qf, qg, qh);
    PACK_SLOT(4, qa, qb, qc, qd);
    PACK_SLOT(5, qe, qf, qg, qh);
    LOADQ_NC(6, qa, qb, qc, qd);     // prefetch pair 6

    COMPUTE(0);
    PACK_SLOT(0, qa, qb, qc, qd);    // pair 6 -> slot 0
    LOADQ_NC(7, qe, qf, qg, qh);
    COMPUTE(1);
    PACK_SLOT(1, qe, qf, qg, qh);    // pair 7 -> slot 1
    LOADQ_NC(8, qa, qb, qc, qd);
    COMPUTE(2);
    PACK_SLOT(2, qa, qb, qc, qd);    // pair 8 -> slot 2
    LOADQ_NC(9, qe, qf, qg, qh);
    COMPUTE(3);
    PACK_SLOT(3, qe, qf, qg, qh);    // pair 9 -> slot 3
    COMPUTE(4);
  } else {
    // ---------- boundary (2 of 32 stripes): compact checked loop ----------
    float qa[5], qb[5], qc[5], qd[5];
    LOADQ_CK(0, qa, qb, qc, qd); PACK_SLOT(0, qa, qb, qc, qd);
    LOADQ_CK(1, qa, qb, qc, qd); PACK_SLOT(1, qa, qb, qc, qd);
    LOADQ_CK(2, qa, qb, qc, qd); PACK_SLOT(2, qa, qb, qc, qd);
    LOADQ_CK(3, qa, qb, qc, qd); PACK_SLOT(3, qa, qb, qc, qd);
    LOADQ_CK(4, qa, qb, qc, qd); PACK_SLOT(4, qa, qb, qc, qd);
    LOADQ_CK(5, qa, qb, qc, qd); PACK_SLOT(5, qa, qb, qc, qd);
#pragma unroll 1
    for (int it = 0; it < TH / 2; ++it) {
      COMPUTE(0);
      if (it < TH / 2 - 1) {
#pragma unroll
        for (int j = 0; j < 5; ++j)
#pragma unroll
          for (int c = 0; c < 5; ++c) {
            rp[j][c] = rp[j + 1][c];
            rt[j][c] = rt[j + 1][c];
          }
        LOADQ_CK(it + 6, qa, qb, qc, qd);
        PACK_SLOT(5, qa, qb, qc, qd);
      }
    }
  }

  // ---- wave reduce + spread atomics ----
#pragma unroll
  for (int off = 32; off; off >>= 1) acc += __shfl_xor(acc, off, 64);
  if (lane == 0)
    atomicAdd(sink + (stripe & (nslot - 1)) * sstr, acc);

  // ---- last-wave fused finalize ----
  __threadfence();
  int last = 0;
  if (lane == 0) last = (atomicAdd(cnt, 1) == NWAVE - 1) ? 1 : 0;
  last = __shfl(last, 0, 64);
  if (last) {
    __threadfence();
    float v = 0.f;
    for (int s = lane; s < nslot; s += 64)
      v += __hip_atomic_load(sink + s * sstr, __ATOMIC_RELAXED,
                             __HIP_MEMORY_SCOPE_AGENT);
#pragma unroll
    for (int off = 32; off; off >>= 1) v += __shfl_xor(v, off, 64);
    if (lane == 0) out[0] = 1.f - v / 13107200.f;
  }
}

// Fallback pair (used only if ws too small for slots+counter).
__global__ void ssim_final(const float* __restrict__ sink, int nslot, int sstr,
                           float* __restrict__ out) {
  const int tid = threadIdx.x;
  float v = 0.f;
  for (int s = tid; s < nslot; s += 64) v += sink[s * sstr];
#pragma unroll
  for (int off = 32; off; off >>= 1) v += __shfl_xor(v, off, 64);
  if (tid == 0) out[0] = 1.f - v / 13107200.f;
}

__global__ __launch_bounds__(256) void ssim_main_nofuse(
    const float* __restrict__ pred, const float* __restrict__ targ,
    float* __restrict__ sink) {
  // minimal fallback: single-slot accumulation (same math, rolled loop)
  const int lane = threadIdx.x & 63;
  const int stripe = __builtin_amdgcn_readfirstlane(
      blockIdx.x * WPB + (threadIdx.x >> 6));
  const int img = stripe / NSTRIPE;
  const int y0  = (stripe % NSTRIPE) * TH;
  const float* __restrict__ P = pred + (size_t)img * (W * H) + 5 * lane;
  const float* __restrict__ T = targ + (size_t)img * (W * H) + 5 * lane;
  constexpr float WF[11] = {0.00102838f, 0.00759885f, 0.03600081f, 0.10936069f,
                            0.21300553f, 0.26601171f, 0.21300553f, 0.10936069f,
                            0.03600081f, 0.00759885f, 0.00102838f};
  const h2 wAv[6] = {pack2(WF[0], WF[1]),  pack2(WF[2], WF[3]),
                     pack2(WF[4], WF[5]),  pack2(WF[6], WF[7]),
                     pack2(WF[8], WF[9]),  pack2(WF[10], 0.f)};
  const h2 wBv[6] = {pack2(0.f, WF[0]),    pack2(WF[1], WF[2]),
                     pack2(WF[3], WF[4]),  pack2(WF[5], WF[6]),
                     pack2(WF[7], WF[8]),  pack2(WF[9], WF[10])};
  h2 WH[11];
#pragma unroll
  for (int k = 0; k < 11; ++k) WH[k] = pack2(WF[k], WF[k]);
  h2 rp[6][5], rt[6][5];
  float acc = 0.f;
  float qa[5], qb[5], qc[5], qd[5];
  LOADQ_CK(0, qa, qb, qc, qd); PACK_SLOT(0, qa, qb, qc, qd);
  LOADQ_CK(1, qa, qb, qc, qd); PACK_SLOT(1, qa, qb, qc, qd);
  LOADQ_CK(2, qa, qb, qc, qd); PACK_SLOT(2, qa, qb, qc, qd);
  LOADQ_CK(3, qa, qb, qc, qd); PACK_SLOT(3, qa, qb, qc, qd);
  LOADQ_CK(4, qa, qb, qc, qd); PACK_SLOT(4, qa, qb, qc, qd);
  LOADQ_CK(5, qa, qb, qc, qd); PACK_SLOT(5, qa, qb, qc, qd);
#pragma unroll 1
  for (int it = 0; it < TH / 2; ++it) {
    COMPUTE(0);
    if (it < TH / 2 - 1) {
#pragma unroll
      for (int j = 0; j < 5; ++j)
#pragma unroll
        for (int c = 0; c < 5; ++c) {
          rp[j][c] = rp[j + 1][c];
          rt[j][c] = rt[j + 1][c];
        }
      LOADQ_CK(it + 6, qa, qb, qc, qd);
      PACK_SLOT(5, qa, qb, qc, qd);
    }
  }
#pragma unroll
  for (int off = 32; off; off >>= 1) acc += __shfl_xor(acc, off, 64);
  if (lane == 0) atomicAdd(sink, acc);
}

__global__ void ssim_final1(float* __restrict__ out) {
  out[0] = 1.f - out[0] / 13107200.f;
}

extern "C" void kernel_launch(void* const* d_in, const int* in_sizes, int n_in,
                              void* d_out, int out_size, void* d_ws, size_t ws_size,
                              hipStream_t stream) {
  (void)in_sizes; (void)n_in; (void)out_size;
  const float* pred = (const float*)d_in[0];
  const float* targ = (const float*)d_in[1];
  float* out = (float*)d_out;

  const size_t need = (size_t)NSLOT * SSTR * sizeof(float) + 16;
  if (ws_size >= need) {
    float* sink = (float*)d_ws;
    int* cnt = (int*)((char*)d_ws + (size_t)NSLOT * SSTR * sizeof(float));
    (void)hipMemsetAsync(d_ws, 0, need, stream);
    ssim_main<<<dim3(NBLK), dim3(256), 0, stream>>>(pred, targ, sink, cnt,
                                                    NSLOT, SSTR, out);
  } else {
    (void)hipMemsetAsync(out, 0, sizeof(float), stream);
    ssim_main_nofuse<<<dim3(NBLK), dim3(256), 0, stream>>>(pred, targ, out);
    ssim_final1<<<1, 1, 0, stream>>>(out);
  }
}

// Round 9
// 60.849 us; speedup vs baseline: 3.3419x; 3.3419x over previous
//
#include <hip/hip_runtime.h>

// SSIM loss v8: v5 structure (rolled TH=10 loop, staggered preamble) with
// DPP wave_shr1/shl1 halo exchange (replaces ds_bpermute shuffles+cndmask;
// semantics HW-verified in v7) and v_cvt_pkrtz f16 packing.

namespace {
constexpr int W = 320, H = 320, B = 128;
constexpr int TH = 10;
constexpr int NSTRIPE = H / TH;     // 32
constexpr int WPB = 4;              // waves per block
constexpr int NWAVE = B * NSTRIPE;  // 4096
constexpr int NBLK = NWAVE / WPB;   // 1024
constexpr int ITERS = TH / 2;       // 5
constexpr float C1 = 1.0e-4f;
constexpr float C2 = 9.0e-4f;
constexpr int NSLOT = 128;
constexpr int SSTR = 16;
}

typedef _Float16 h2 __attribute__((ext_vector_type(2)));

__device__ __forceinline__ float fdot2f(h2 a, h2 b, float c) {
#if __has_builtin(__builtin_amdgcn_fdot2)
  return __builtin_amdgcn_fdot2(a, b, c, false);
#else
  return fmaf((float)a.x, (float)b.x, fmaf((float)a.y, (float)b.y, c));
#endif
}

__device__ __forceinline__ float rcpf(float x) {
  float r;
  asm("v_rcp_f32 %0, %1" : "=v"(r) : "v"(x));
  return r;
}

__device__ __forceinline__ h2 pack2(float a, float b) {
  return h2{(_Float16)a, (_Float16)b};
}

__device__ __forceinline__ h2 pkrtz(float a, float b) {
#if __has_builtin(__builtin_amdgcn_cvt_pkrtz)
  return __builtin_bit_cast(h2, __builtin_amdgcn_cvt_pkrtz(a, b));
#else
  return pack2(a, b);
#endif
}

// lane i <- lane i-1, lane 0 <- 0 (wave_shr:1, bound_ctrl).  [verified v7]
__device__ __forceinline__ h2 dpp_up1(h2 v) {
  int r = __builtin_amdgcn_update_dpp(0, __builtin_bit_cast(int, v),
                                      0x138, 0xF, 0xF, true);
  return __builtin_bit_cast(h2, r);
}
// lane i <- lane i+1, lane 63 <- 0 (wave_shl:1, bound_ctrl).  [verified v7]
__device__ __forceinline__ h2 dpp_dn1(h2 v) {
  int r = __builtin_amdgcn_update_dpp(0, __builtin_bit_cast(int, v),
                                      0x130, 0xF, 0xF, true);
  return __builtin_bit_cast(h2, r);
}

#define LOADP_RAW(ROW, A0, B0, A1, B1)                                        \
  do {                                                                        \
    const int r0_ = (ROW);                                                    \
    if (r0_ >= 0 && r0_ < H) {                                                \
      const float* p_ = P + r0_ * W;                                          \
      const float* t_ = T + r0_ * W;                                          \
      _Pragma("unroll") for (int c_ = 0; c_ < 5; ++c_) {                      \
        A0[c_] = p_[c_]; B0[c_] = t_[c_];                                     \
      }                                                                       \
    } else {                                                                  \
      _Pragma("unroll") for (int c_ = 0; c_ < 5; ++c_) {                      \
        A0[c_] = 0.f; B0[c_] = 0.f;                                           \
      }                                                                       \
    }                                                                         \
    if (r0_ + 1 >= 0 && r0_ + 1 < H) {                                        \
      const float* p_ = P + (r0_ + 1) * W;                                    \
      const float* t_ = T + (r0_ + 1) * W;                                    \
      _Pragma("unroll") for (int c_ = 0; c_ < 5; ++c_) {                      \
        A1[c_] = p_[c_]; B1[c_] = t_[c_];                                     \
      }                                                                       \
    } else {                                                                  \
      _Pragma("unroll") for (int c_ = 0; c_ < 5; ++c_) {                      \
        A1[c_] = 0.f; B1[c_] = 0.f;                                           \
      }                                                                       \
    }                                                                         \
  } while (0)

#define PACKTO(J, A0, B0, A1, B1)                                             \
  do {                                                                        \
    _Pragma("unroll") for (int c_ = 0; c_ < 5; ++c_) {                        \
      rp[J][c_] = pkrtz(A0[c_], A1[c_]);                                      \
      rt[J][c_] = pkrtz(B0[c_], B1[c_]);                                      \
    }                                                                         \
  } while (0)

// DPP halo: 10 VALU movs per channel, zero-pad built in.
#define HALO(PKc, L, R)                                                       \
  do {                                                                        \
    _Pragma("unroll") for (int c_ = 0; c_ < 5; ++c_) {                        \
      L[c_] = dpp_up1(PKc[c_]);                                               \
      R[c_] = dpp_dn1(PKc[c_]);                                               \
    }                                                                         \
  } while (0)

#define HBLUR(PKc, L, R, O)                                                   \
  do {                                                                        \
    _Pragma("unroll") for (int c_ = 0; c_ < 5; ++c_) {                        \
      h2 s1_ = WH[0] * ((c_ + 0 < 5) ? L[c_] : PKc[c_ - 5]);                  \
      _Pragma("unroll") for (int k_ = 1; k_ < 5; ++k_) {                      \
        const int i_ = c_ + k_;                                               \
        s1_ = WH[k_] * ((i_ < 5) ? L[i_] : PKc[i_ - 5]) + s1_;                \
      }                                                                       \
      h2 s2_ = WH[10] * R[c_];                                                \
      _Pragma("unroll") for (int k_ = 9; k_ >= 5; --k_) {                     \
        const int i_ = c_ + k_;                                               \
        s2_ = WH[k_] * ((i_ < 10) ? PKc[i_ - 5] : R[i_ - 10]) + s2_;          \
      }                                                                       \
      O[c_] = s1_ + s2_;                                                      \
    }                                                                         \
  } while (0)

__global__ __launch_bounds__(256) void ssim_main(
    const float* __restrict__ pred, const float* __restrict__ targ,
    float* __restrict__ sink, int slotmask, int sstr) {
  const int lane = threadIdx.x & 63;
  const int wid  = threadIdx.x >> 6;
  const int stripe = blockIdx.x * WPB + wid;
  const int img = stripe / NSTRIPE;
  const int y0  = (stripe % NSTRIPE) * TH;

  const float* __restrict__ P = pred + (size_t)img * (W * H) + 5 * lane;
  const float* __restrict__ T = targ + (size_t)img * (W * H) + 5 * lane;

  constexpr float WF[11] = {0.00102838f, 0.00759885f, 0.03600081f, 0.10936069f,
                            0.21300553f, 0.26601171f, 0.21300553f, 0.10936069f,
                            0.03600081f, 0.00759885f, 0.00102838f};
  const h2 wAv[6] = {pack2(WF[0], WF[1]),  pack2(WF[2], WF[3]),
                     pack2(WF[4], WF[5]),  pack2(WF[6], WF[7]),
                     pack2(WF[8], WF[9]),  pack2(WF[10], 0.f)};
  const h2 wBv[6] = {pack2(0.f, WF[0]),    pack2(WF[1], WF[2]),
                     pack2(WF[3], WF[4]),  pack2(WF[5], WF[6]),
                     pack2(WF[7], WF[8]),  pack2(WF[9], WF[10])};
  h2 WH[11];
#pragma unroll
  for (int k = 0; k < 11; ++k) WH[k] = pack2(WF[k], WF[k]);

  h2 rp[6][5], rt[6][5];
  float nfA[5], ntA[5], nfB[5], ntB[5];

  // ---- staggered preamble: 2 row-pairs in flight ----
  {
    float aA[5], bA[5], cA[5], dA[5];
    float aB[5], bB[5], cB[5], dB[5];
    LOADP_RAW(y0 - 5, aA, bA, cA, dA);
    LOADP_RAW(y0 - 3, aB, bB, cB, dB);
    PACKTO(1, aA, bA, cA, dA);
    LOADP_RAW(y0 - 1, aA, bA, cA, dA);
    PACKTO(2, aB, bB, cB, dB);
    LOADP_RAW(y0 + 1, aB, bB, cB, dB);
    PACKTO(3, aA, bA, cA, dA);
    LOADP_RAW(y0 + 3, aA, bA, cA, dA);
    PACKTO(4, aB, bB, cB, dB);
    LOADP_RAW(y0 + 5, nfA, ntA, nfB, ntB);
    PACKTO(5, aA, bA, cA, dA);
  }

  float acc = 0.f;

#pragma unroll 1
  for (int it = 0; it < ITERS; ++it) {
    // slide ring; pack last iteration's prefetch; issue next loads.
#pragma unroll
    for (int j = 0; j < 5; ++j)
#pragma unroll
      for (int c = 0; c < 5; ++c) {
        rp[j][c] = rp[j + 1][c];
        rt[j][c] = rt[j + 1][c];
      }
    PACKTO(5, nfA, ntA, nfB, ntB);
    if (it + 1 < ITERS) LOADP_RAW(y0 + 2 * it + 7, nfA, ntA, nfB, ntB);

    // ---- vertical 11-tap blur (3 pk_mul + 10 dot2 per col) ----
    h2 PK[5][5];  // [ch][col], two output rows packed
#pragma unroll
    for (int c = 0; c < 5; ++c) {
      float mpA = 0, mtA = 0, ppA = 0, ttA = 0, ptA = 0;
      float mpB = 0, mtB = 0, ppB = 0, ttB = 0, ptB = 0;
#pragma unroll
      for (int j = 0; j < 6; ++j) {
        const h2 a = rp[j][c], b = rt[j][c];
        const h2 aa = a * a, bb = b * b, ab = a * b;
        const h2 wa = wAv[j], wb = wBv[j];
        mpA = fdot2f(wa, a, mpA);
        mtA = fdot2f(wa, b, mtA);
        ppA = fdot2f(wa, aa, ppA);
        ttA = fdot2f(wa, bb, ttA);
        ptA = fdot2f(wa, ab, ptA);
        mpB = fdot2f(wb, a, mpB);
        mtB = fdot2f(wb, b, mtB);
        ppB = fdot2f(wb, aa, ppB);
        ttB = fdot2f(wb, bb, ttB);
        ptB = fdot2f(wb, ab, ptB);
      }
      PK[0][c] = pkrtz(mpA, mpB);
      PK[1][c] = pkrtz(mtA, mtB);
      PK[2][c] = pkrtz(ppA, ppB);
      PK[3][c] = pkrtz(ttA, ttB);
      PK[4][c] = pkrtz(ptA, ptB);
    }

    // ---- horizontal blur: DPP halo (pure VALU) + pk_fma ----
    h2 OUT[5][5];
#pragma unroll
    for (int ch = 0; ch < 5; ++ch) {
      h2 L[5], R[5];
      HALO(PK[ch], L, R);
      HBLUR(PK[ch], L, R, OUT[ch]);
    }

    // ---- SSIM map + accumulate ----
#pragma unroll
    for (int c = 0; c < 5; ++c) {
#pragma unroll
      for (int r = 0; r < 2; ++r) {
        const float mx = r ? (float)OUT[0][c].y : (float)OUT[0][c].x;
        const float my = r ? (float)OUT[1][c].y : (float)OUT[1][c].x;
        const float xx = r ? (float)OUT[2][c].y : (float)OUT[2][c].x;
        const float yy = r ? (float)OUT[3][c].y : (float)OUT[3][c].x;
        const float xy = r ? (float)OUT[4][c].y : (float)OUT[4][c].x;
        const float mxx = mx * mx, myy = my * my, mxy = mx * my;
        const float vx = xx - mxx, vy = yy - myy, vxy = xy - mxy;
        const float num = (2.f * mxy + C1) * (2.f * vxy + C2);
        const float den = (mxx + myy + C1) * (vx + vy + C2);
        acc = fmaf(num, rcpf(den), acc);
      }
    }
  }

  // ---- wave reduce + spread atomics ----
#pragma unroll
  for (int off = 32; off; off >>= 1) acc += __shfl_xor(acc, off, 64);
  if (lane == 0) atomicAdd(sink + (stripe & slotmask) * sstr, acc);
}

__global__ void ssim_final(const float* __restrict__ sink, int nslot, int sstr,
                           float* __restrict__ out) {
  const int tid = threadIdx.x;  // 64 threads
  float v = 0.f;
  for (int s = tid; s < nslot; s += 64) v += sink[s * sstr];
#pragma unroll
  for (int off = 32; off; off >>= 1) v += __shfl_xor(v, off, 64);
  if (tid == 0) out[0] = 1.f - v / 13107200.f;
}

extern "C" void kernel_launch(void* const* d_in, const int* in_sizes, int n_in,
                              void* d_out, int out_size, void* d_ws, size_t ws_size,
                              hipStream_t stream) {
  (void)in_sizes; (void)n_in; (void)out_size;
  const float* pred = (const float*)d_in[0];
  const float* targ = (const float*)d_in[1];
  float* out = (float*)d_out;

  float* sink;
  int nslot, sstr;
  const size_t need = (size_t)NSLOT * SSTR * sizeof(float);
  if (ws_size >= need) {
    sink = (float*)d_ws;
    nslot = NSLOT;
    sstr = SSTR;
  } else {
    sink = out;
    nslot = 1;
    sstr = 0;
  }
  (void)hipMemsetAsync(sink, 0, nslot == 1 ? sizeof(float) : need, stream);
  ssim_main<<<dim3(NBLK), dim3(256), 0, stream>>>(pred, targ, sink, nslot - 1, sstr);
  ssim_final<<<1, 64, 0, stream>>>(sink, nslot, sstr, out);
}